// Round 11
// baseline (181.078 us; speedup 1.0000x reference)
//
#include <hip/hip_runtime.h>

typedef unsigned short u16;
typedef __bf16 bf16x8 __attribute__((ext_vector_type(8)));
typedef float f32x4 __attribute__((ext_vector_type(4)));
typedef u16 u16x8 __attribute__((ext_vector_type(8)));

#define B_ 16384

__device__ __forceinline__ u16 f2b(float f){
  unsigned u = __builtin_bit_cast(unsigned, f);
  u = (u + 0x7FFFu + ((u >> 16) & 1u)) >> 16;   // RNE
  return (u16)u;
}
__device__ __forceinline__ float b2f(u16 v){
  return __builtin_bit_cast(float, ((unsigned)v) << 16);
}
__device__ __forceinline__ void ld8(const u16* __restrict__ p, float* f){
  u16x8 v = *(const u16x8*)p;
  #pragma unroll
  for (int j = 0; j < 8; ++j) f[j] = b2f(v[j]);
}
__device__ __forceinline__ void st8(u16* __restrict__ p, const float* f){
  u16x8 v;
  #pragma unroll
  for (int j = 0; j < 8; ++j) v[j] = f2b(f[j]);
  *(u16x8*)p = v;
}

__device__ __forceinline__ void gload16(const u16* g, u16* lds){
  __builtin_amdgcn_global_load_lds(
      (const __attribute__((address_space(1))) unsigned int*)g,
      (__attribute__((address_space(3))) unsigned int*)lds, 16, 0, 0);
}

// ===== core32w: BM=128, BN=256, BK=32, 4 waves, per-wave 64x128 (acc[4][8]) =
// R9 core32 skeleton (ring-3, counted vmcnt, row-pair 0-conflict swizzle,
// 2 blocks/CU) with a WIDER wave tile: 48KB LDS-read per 128 MFMA per block
// per K-step (vs 64KB at 64x64 waves) and 4-wave barriers (vs 8).
// LDS slot = A[128][32] + B[256][32] = 24KB; ring-3 = 72KB -> 2 blocks/CU.
// Layout (R9-verified, 0 conflicts): 128B lines hold row-pairs (2L,2L+1);
// logical slot s' = (r&1)*4 + k4, phys = s' ^ (L&7); staged via pre-swizzled
// global source (s' = (l&7)^((l>>3)&7), chunk-independent) + linear LDS dest.
// Schedule per step j: STAGE(j+2) -> ds_read av[4],bv[8] -> 32 MFMA ->
// vmcnt(6) (j+1 landed; never drain-0 in steady state) -> barrier.
__device__ __forceinline__ void core32w(const u16* __restrict__ A,
                                        const u16* __restrict__ Wt,
                                        int K, int m0, int n0, int nt,
                                        u16* sm, f32x4 acc[4][8])
{
  const int tid = threadIdx.x, lane = tid & 63, wave = tid >> 6;  // 0..3
  const int wm = ((tid >> 7) & 1) * 64;
  const int wn = ((tid >> 6) & 1) * 128;

  #pragma unroll
  for (int m = 0; m < 4; ++m)
    #pragma unroll
    for (int n = 0; n < 8; ++n) acc[m][n] = (f32x4){0.f, 0.f, 0.f, 0.f};

  // staging: 24 chunks of 1KB (A: c<8 rows c*16.., B: c>=8), 6 per wave
  const int s_    = (lane & 7) ^ ((lane >> 3) & 7);
  const int srow2 = 2 * (lane >> 3) + (s_ >> 2);
  const int sk    = (s_ & 3) * 8;
  const u16* gsrc[6];
  int gdst[6];
  #pragma unroll
  for (int i = 0; i < 6; ++i) {
    int c = wave * 6 + i;
    if (c < 8) {
      gsrc[i] = A + (size_t)(m0 + c * 16 + srow2) * K + sk;
      gdst[i] = c * 512;
    } else {
      gsrc[i] = Wt + (size_t)(n0 + (c - 8) * 16 + srow2) * K + sk;
      gdst[i] = 4096 + (c - 8) * 512;
    }
  }

  int aoff[4], boff[8];
  #pragma unroll
  for (int m = 0; m < 4; ++m) {
    int r = wm + m * 16 + (lane & 15);
    int L = r >> 1;
    int phys = (((r & 1) << 2) + (lane >> 4)) ^ (L & 7);
    aoff[m] = L * 64 + phys * 8;
  }
  #pragma unroll
  for (int n = 0; n < 8; ++n) {
    int r = wn + n * 16 + (lane & 15);
    int L = r >> 1;
    int phys = (((r & 1) << 2) + (lane >> 4)) ^ (L & 7);
    boff[n] = 4096 + L * 64 + phys * 8;
  }

  // prologue: stage steps 0,1 into slots 0,1
  #pragma unroll
  for (int j = 0; j < 2; ++j) {
    u16* sl = sm + j * 12288;
    #pragma unroll
    for (int i = 0; i < 6; ++i) gload16(gsrc[i] + j * 32, sl + gdst[i]);
  }
  asm volatile("s_waitcnt vmcnt(6)" ::: "memory");   // step 0 landed
  __builtin_amdgcn_s_barrier();

  int cs = 0;
  for (int j = 0; j < nt; ++j) {
    if (j + 2 < nt) {
      int ns = cs + 2; ns = (ns >= 3) ? ns - 3 : ns;
      u16* sl = sm + ns * 12288;
      #pragma unroll
      for (int i = 0; i < 6; ++i) gload16(gsrc[i] + (size_t)(j + 2) * 32, sl + gdst[i]);
    }
    const u16* sa = sm + cs * 12288;
    bf16x8 av[4], bv[8];
    #pragma unroll
    for (int m = 0; m < 4; ++m) av[m] = *(const bf16x8*)(sa + aoff[m]);
    #pragma unroll
    for (int n = 0; n < 8; ++n) bv[n] = *(const bf16x8*)(sa + boff[n]);
    __builtin_amdgcn_s_setprio(1);
    #pragma unroll
    for (int m = 0; m < 4; ++m)
      #pragma unroll
      for (int n = 0; n < 8; ++n)
        acc[m][n] = __builtin_amdgcn_mfma_f32_16x16x32_bf16(av[m], bv[n], acc[m][n], 0, 0, 0);
    __builtin_amdgcn_s_setprio(0);
    if (j + 2 < nt)      asm volatile("s_waitcnt vmcnt(6)" ::: "memory");
    else if (j + 1 < nt) asm volatile("s_waitcnt vmcnt(0)" ::: "memory");
    __builtin_amdgcn_s_barrier();
    cs = (cs == 2) ? 0 : cs + 1;
  }
}

// ---------------- stage kernels ----------------

// GEMM0: xb[16384,512] x Wt0[2560,512]^T (de-padded, experts only).
// grid 1280 = 128 m x 10 n-panels(256), XCD-swizzled.
__global__ __launch_bounds__(256, 2) void k_gemm0(const u16* __restrict__ xb,
    const u16* __restrict__ Wt0, const float* __restrict__ bias0,
    u16* __restrict__ E0)
{
  __shared__ __align__(16) u16 sm[36864];
  f32x4 acc[4][8];
  const int bid = blockIdx.x;                 // 1280 = 8 * 160
  const int swz = (bid & 7) * 160 + (bid >> 3);
  const int m0 = (swz / 10) * 128, n0 = (swz % 10) * 256;
  core32w(xb, Wt0, 512, m0, n0, 16, sm, acc);
  const int lane = threadIdx.x & 63;
  const int wm = ((threadIdx.x >> 7) & 1) * 64, wn = ((threadIdx.x >> 6) & 1) * 128;
  #pragma unroll
  for (int mi = 0; mi < 4; ++mi)
    #pragma unroll
    for (int ni = 0; ni < 8; ++ni) {
      int gcol = n0 + wn + ni * 16 + (lane & 15);
      float bias = bias0[gcol];
      #pragma unroll
      for (int q = 0; q < 4; ++q) {
        int grow = m0 + wm + mi * 16 + ((lane >> 4) << 2) + q;
        E0[(size_t)grow * 2560 + gcol] = f2b(fmaxf(acc[mi][ni][q] + bias, 0.f));
      }
    }
}

// MIX0 + gate0 + gate1 fused: 8 rows/block, one 32-lane half-wave per row.
// Gate0: 26 logits per row = dot(xb_row, WG0T[g]) via 16 elems/lane +
// 32-lane shuffle reduce (same trick as the proven gate1 fusion).
__global__ __launch_bounds__(256) void k_mix0(const u16* __restrict__ E0,
    const u16* __restrict__ xb, const u16* __restrict__ WG0T,
    const float* __restrict__ b_gate0, const float* __restrict__ b_gsh0,
    const float* __restrict__ WG1T, const float* __restrict__ b_gate1,
    u16* __restrict__ T1SH, float* __restrict__ G1S)
{
  const int b = blockIdx.x * 8 + (threadIdx.x >> 5);
  const int l32 = threadIdx.x & 31;
  const int e0 = l32 * 8;

  // ---- gate0: 26 logits from xb ----
  float xf[16];
  ld8(xb + (size_t)b * 512 + l32 * 16, xf);
  ld8(xb + (size_t)b * 512 + l32 * 16 + 8, xf + 8);
  float lg[26];
  #pragma unroll
  for (int g = 0; g < 26; ++g) {
    float w0[8], w1[8];
    ld8(WG0T + (size_t)g * 512 + l32 * 16, w0);
    ld8(WG0T + (size_t)g * 512 + l32 * 16 + 8, w1);
    float s = 0.f;
    #pragma unroll
    for (int j = 0; j < 8; ++j) s += xf[j] * w0[j] + xf[8 + j] * w1[j];
    #pragma unroll
    for (int off = 1; off < 32; off <<= 1) s += __shfl_xor(s, off, 32);
    lg[g] = s + ((g < 16) ? b_gate0[g] : b_gsh0[g - 16]);
  }
  float g[4][4];
  #pragma unroll
  for (int t = 0; t < 4; ++t) {
    float l0 = lg[t*4+0], l1 = lg[t*4+1], l2 = lg[t*4+2], l3 = lg[t*4+3];
    float m = fmaxf(fmaxf(l0, l1), fmaxf(l2, l3));
    float e0e = expf(l0-m), e1 = expf(l1-m), e2 = expf(l2-m), e3 = expf(l3-m);
    float inv = 1.f / (e0e + e1 + e2 + e3);
    g[t][0] = e0e*inv; g[t][1] = e1*inv; g[t][2] = e2*inv; g[t][3] = e3*inv;
  }
  float gs[10];
  {
    float m = lg[16];
    #pragma unroll
    for (int j = 1; j < 10; ++j) m = fmaxf(m, lg[16 + j]);
    float s = 0.f;
    #pragma unroll
    for (int j = 0; j < 10; ++j) { gs[j] = expf(lg[16 + j] - m); s += gs[j]; }
    float inv = 1.f / s;
    #pragma unroll
    for (int j = 0; j < 10; ++j) gs[j] *= inv;
  }

  // ---- mixing + gate1 logits ----
  const u16* row = E0 + (size_t)b * 2560;
  float sh0[8], sh1[8], shacc[8];
  ld8(row + 2048 + e0, sh0);
  ld8(row + 2304 + e0, sh1);
  #pragma unroll
  for (int j = 0; j < 8; ++j) shacc[j] = gs[8]*sh0[j] + gs[9]*sh1[j];
  float gp[16];
  #pragma unroll
  for (int t = 0; t < 4; ++t) {
    float te0[8], te1[8], v[8];
    ld8(row + (t*2+0)*256 + e0, te0);
    ld8(row + (t*2+1)*256 + e0, te1);
    #pragma unroll
    for (int j = 0; j < 8; ++j) {
      v[j] = g[t][0]*te0[j] + g[t][1]*te1[j] + g[t][2]*sh0[j] + g[t][3]*sh1[j];
      shacc[j] += gs[t*2+0]*te0[j] + gs[t*2+1]*te1[j];
    }
    st8(T1SH + ((size_t)t * B_ + b) * 256 + e0, v);
    #pragma unroll
    for (int gg = 0; gg < 4; ++gg) {
      const float* wv = WG1T + ((size_t)(t * 4 + gg) * 256 + e0);
      float s = 0.f;
      #pragma unroll
      for (int j = 0; j < 8; ++j) s += v[j] * wv[j];
      gp[t * 4 + gg] = s;
    }
  }
  st8(T1SH + ((size_t)4 * B_ + b) * 256 + e0, shacc);
  #pragma unroll
  for (int i = 0; i < 16; ++i) {
    #pragma unroll
    for (int off = 1; off < 32; off <<= 1)
      gp[i] += __shfl_xor(gp[i], off, 32);
  }
  if (l32 == 0) {
    float* orow = G1S + (size_t)b * 16;
    #pragma unroll
    for (int z = 0; z < 4; ++z) {
      float l0 = gp[z*4+0] + b_gate1[z*4+0];
      float l1 = gp[z*4+1] + b_gate1[z*4+1];
      float l2 = gp[z*4+2] + b_gate1[z*4+2];
      float l3 = gp[z*4+3] + b_gate1[z*4+3];
      float m = fmaxf(fmaxf(l0, l1), fmaxf(l2, l3));
      float x0 = expf(l0-m), x1 = expf(l1-m), x2 = expf(l2-m), x3 = expf(l3-m);
      float inv = 1.f / (x0 + x1 + x2 + x3);
      orow[z*4+0] = x0*inv; orow[z*4+1] = x1*inv;
      orow[z*4+2] = x2*inv; orow[z*4+3] = x3*inv;
    }
  }
}

// GEMM1: 10 panels (5 z x 2 n-panels of 256) x 128 m-blocks, core32w.
__global__ __launch_bounds__(256, 2) void k_gemm1(const u16* __restrict__ T1SH,
    const u16* __restrict__ Wt1, const float* __restrict__ bias1,
    u16* __restrict__ E1, u16* __restrict__ SH1E)
{
  __shared__ __align__(16) u16 sm[36864];
  f32x4 acc[4][8];
  const int bid = blockIdx.x;                 // 1280 = 8 * 160
  const int swz = (bid & 7) * 160 + (bid >> 3);
  const int mi_ = swz / 10, pan = swz % 10;
  const int z  = pan >> 1;
  const int n0 = (pan & 1) * 256;
  const int m0 = mi_ * 128;
  core32w(T1SH + (size_t)z * B_ * 256, Wt1 + (size_t)z * 512 * 256, 256, m0, n0, 8, sm, acc);
  const int lane = threadIdx.x & 63;
  const int wm = ((threadIdx.x >> 7) & 1) * 64, wn = ((threadIdx.x >> 6) & 1) * 128;
  const float* bias = bias1 + z * 512;
  #pragma unroll
  for (int mi = 0; mi < 4; ++mi)
    #pragma unroll
    for (int ni = 0; ni < 8; ++ni) {
      int gcol = n0 + wn + ni * 16 + (lane & 15);
      float bv = bias[gcol];
      #pragma unroll
      for (int q = 0; q < 4; ++q) {
        int grow = m0 + wm + mi * 16 + ((lane >> 4) << 2) + q;
        float v = fmaxf(acc[mi][ni][q] + bv, 0.f);
        if (z < 4) E1[((size_t)z * B_ + grow) * 512 + gcol] = f2b(v);
        else       SH1E[(size_t)grow * 512 + gcol] = f2b(v);
      }
    }
}

// TOWER2 (mix1 fused, R10-proven): A-tile = t2[z] built during reg-staging.
__global__ __launch_bounds__(256) void k_tower2(const u16* __restrict__ E1,
    const u16* __restrict__ SH1E, const float* __restrict__ G1S,
    const u16* __restrict__ Wtw, const float* __restrict__ b_tw,
    const float* __restrict__ w_out, const float* __restrict__ b_out,
    float* __restrict__ out)
{
  __shared__ __align__(16) u16 sm[32768];
  __shared__ float part[2][128][2];
  f32x4 acc[4][4];
  const int z = blockIdx.z;
  const int m0 = blockIdx.x * 128;
  const int tid = threadIdx.x, lane = tid & 63, wave = tid >> 6;
  const int wm = ((tid >> 7) & 1) * 64, wn = ((tid >> 6) & 1) * 64;

  #pragma unroll
  for (int mi = 0; mi < 4; ++mi)
    #pragma unroll
    for (int ni = 0; ni < 4; ++ni) acc[mi][ni] = (f32x4){0.f, 0.f, 0.f, 0.f};

  const int srow  = lane >> 3;
  const int gslot = (lane & 7) ^ srow;
  const int koff0 = gslot * 8;

  int growA[4], adst[4], bdst[4];
  const u16* bsrc[4];
  #pragma unroll
  for (int i = 0; i < 4; ++i) {
    int c = wave * 4 + i;
    growA[i] = m0 + c * 8 + srow;
    adst[i]  = c * 512;
    bsrc[i]  = Wtw + (size_t)z * 128 * 256 + (size_t)(c * 8 + srow) * 256 + koff0;
    bdst[i]  = 8192 + c * 512;
  }
  const u16* E1z = E1 + (size_t)z * B_ * 512;

  int aoff[2][4], boff[2][4];
  #pragma unroll
  for (int kk = 0; kk < 2; ++kk) {
    #pragma unroll
    for (int m = 0; m < 4; ++m) {
      int r = wm + m * 16 + (lane & 15);
      aoff[kk][m] = r * 64 + (((kk * 4 + (lane >> 4)) ^ (r & 7)) * 8);
    }
    #pragma unroll
    for (int n = 0; n < 4; ++n) {
      int r = wn + n * 16 + (lane & 15);
      boff[kk][n] = 8192 + r * 64 + (((kk * 4 + (lane >> 4)) ^ (r & 7)) * 8);
    }
  }

  #define STAGE_T(J, BUF) do {                                                 \
    u16* buf_ = (BUF);                                                         \
    _Pragma("unroll")                                                          \
    for (int i_ = 0; i_ < 4; ++i_) {                                           \
      size_t eoff_ = (size_t)growA[i_] * 512 + (J) * 64 + koff0;               \
      u16x8 ea_ = *(const u16x8*)(E1z + eoff_);                                \
      u16x8 eb_ = *(const u16x8*)(E1z + eoff_ + 256);                          \
      u16x8 sa_ = *(const u16x8*)(SH1E + eoff_);                               \
      u16x8 sb_ = *(const u16x8*)(SH1E + eoff_ + 256);                         \
      float4 g_ = *(const float4*)(G1S + (size_t)growA[i_] * 16 + z * 4);      \
      u16x8 o_;                                                                \
      _Pragma("unroll")                                                        \
      for (int jj_ = 0; jj_ < 8; ++jj_)                                        \
        o_[jj_] = f2b(g_.x * b2f(ea_[jj_]) + g_.y * b2f(eb_[jj_])              \
                    + g_.z * b2f(sa_[jj_]) + g_.w * b2f(sb_[jj_]));            \
      *(uint4*)(buf_ + adst[i_] + lane * 8) = __builtin_bit_cast(uint4, o_);   \
      gload16(bsrc[i_] + (J) * 64, buf_ + bdst[i_]);                           \
    }                                                                          \
  } while (0)

  STAGE_T(0, sm);
  __syncthreads();

  #pragma unroll
  for (int t = 0; t < 4; ++t) {
    if (t + 1 < 4) STAGE_T(t + 1, sm + ((t + 1) & 1) * 16384);
    const u16* sa = sm + (t & 1) * 16384;
    #pragma unroll
    for (int kk = 0; kk < 2; ++kk) {
      bf16x8 av[4], bv[4];
      #pragma unroll
      for (int m = 0; m < 4; ++m) av[m] = *(const bf16x8*)(sa + aoff[kk][m]);
      #pragma unroll
      for (int n = 0; n < 4; ++n) bv[n] = *(const bf16x8*)(sa + boff[kk][n]);
      #pragma unroll
      for (int m = 0; m < 4; ++m)
        #pragma unroll
        for (int n = 0; n < 4; ++n)
          acc[m][n] = __builtin_amdgcn_mfma_f32_16x16x32_bf16(av[m], bv[n], acc[m][n], 0, 0, 0);
    }
    if (t + 1 < 4) __syncthreads();
  }
  #undef STAGE_T

  #pragma unroll
  for (int mi = 0; mi < 4; ++mi) {
    #pragma unroll
    for (int r = 0; r < 4; ++r) {
      float p0 = 0.f, p1 = 0.f;
      #pragma unroll
      for (int ni = 0; ni < 4; ++ni) {
        int col = wn + ni * 16 + (lane & 15);
        float h = fmaxf(acc[mi][ni][r] + b_tw[z * 128 + col], 0.f);
        p0 += h * w_out[(z * 128 + col) * 2 + 0];
        p1 += h * w_out[(z * 128 + col) * 2 + 1];
      }
      #pragma unroll
      for (int off = 1; off < 16; off <<= 1) {
        p0 += __shfl_xor(p0, off);
        p1 += __shfl_xor(p1, off);
      }
      if ((lane & 15) == 0) {
        int rowl = wm + mi * 16 + ((lane >> 4) << 2) + r;
        part[wn >> 6][rowl][0] = p0;
        part[wn >> 6][rowl][1] = p1;
      }
    }
  }
  __syncthreads();
  if (threadIdx.x < 128) {
    int rowl = threadIdx.x;
    float l0 = part[0][rowl][0] + part[1][rowl][0] + b_out[z * 2 + 0];
    float l1 = part[0][rowl][1] + part[1][rowl][1] + b_out[z * 2 + 1];
    float mx = fmaxf(l0, l1);
    float e0 = expf(l0 - mx), e1 = expf(l1 - mx);
    float inv = 1.f / (e0 + e1);
    float p0 = fminf(fmaxf(e0 * inv, 1e-15f), 1.0f);
    float p1 = fminf(fmaxf(e1 * inv, 1e-15f), 1.0f);
    size_t o = ((size_t)z * B_ + m0 + rowl) * 2;
    out[o] = p0; out[o + 1] = p1;
  }
}

// PREP: cast x -> bf16; transposed weight panels + biases + WG0T + WG1T.
__global__ void k_prep(const float* __restrict__ x,
    const float* __restrict__ w_task0, const float* __restrict__ b_task0,
    const float* __restrict__ w_sh0,   const float* __restrict__ b_sh0,
    const float* __restrict__ w_gate0, const float* __restrict__ w_gsh0,
    const float* __restrict__ w_task1, const float* __restrict__ b_task1,
    const float* __restrict__ w_sh1,   const float* __restrict__ b_sh1,
    const float* __restrict__ w_gate1, const float* __restrict__ w_tw,
    u16* __restrict__ xb, u16* __restrict__ Wt0, float* __restrict__ bias0,
    u16* __restrict__ Wt1, float* __restrict__ bias1, u16* __restrict__ Wtw,
    u16* __restrict__ WG0T, float* __restrict__ WG1T)
{
  size_t i = (size_t)blockIdx.x * 256 + threadIdx.x;
  const size_t S_X8  = (size_t)16384 * 512 / 8; // 1048576
  const size_t S_WT0 = (size_t)2560 * 512;      // 1310720
  const size_t S_B0  = 2560;
  const size_t S_WT1 = (size_t)5 * 512 * 256;   // 655360
  const size_t S_B1  = 5 * 512;                 // 2560
  const size_t S_WTW = (size_t)4 * 128 * 256;   // 131072
  const size_t S_WG0 = 26 * 512;                // 13312
  const size_t S_WG1 = 4096;

  if (i < S_X8) {
    size_t o = i * 8;
    float4 a = *(const float4*)(x + o);
    float4 b = *(const float4*)(x + o + 4);
    u16x8 v;
    v[0] = f2b(a.x); v[1] = f2b(a.y); v[2] = f2b(a.z); v[3] = f2b(a.w);
    v[4] = f2b(b.x); v[5] = f2b(b.y); v[6] = f2b(b.z); v[7] = f2b(b.w);
    *(u16x8*)(xb + o) = v;
    return;
  }
  i -= S_X8;
  if (i < S_WT0) {
    int c = (int)(i / 512), f = (int)(i % 512);
    float v;
    if (c < 2048) { int te = c >> 8, o = c & 255; v = w_task0[((size_t)te * 512 + f) * 256 + o]; }
    else          { int s = (c - 2048) >> 8, o = c & 255; v = w_sh0[((size_t)s * 512 + f) * 256 + o]; }
    Wt0[i] = f2b(v);
    return;
  }
  i -= S_WT0;
  if (i < S_B0) {
    int c = (int)i; float v;
    if (c < 2048) { int te = c >> 8, o = c & 255; v = b_task0[te * 256 + o]; }
    else          { int s = (c - 2048) >> 8, o = c & 255; v = b_sh0[s * 256 + o]; }
    bias0[c] = v;
    return;
  }
  i -= S_B0;
  if (i < S_WT1) {
    int z = (int)(i / (512 * 256)); int rem = (int)(i % (512 * 256));
    int c = rem / 256, f = rem % 256;
    float v;
    if (z < 4) { int ee = c >> 8, o = c & 255; v = w_task1[(((size_t)(z * 2 + ee)) * 256 + f) * 256 + o]; }
    else       { int s = c >> 8, o = c & 255; v = w_sh1[((size_t)s * 256 + f) * 256 + o]; }
    Wt1[i] = f2b(v);
    return;
  }
  i -= S_WT1;
  if (i < S_B1) {
    int z = (int)(i / 512); int c = (int)(i % 512);
    float v;
    if (z < 4) { int ee = c >> 8, o = c & 255; v = b_task1[(z * 2 + ee) * 256 + o]; }
    else       { int s = c >> 8, o = c & 255; v = b_sh1[s * 256 + o]; }
    bias1[(size_t)z * 512 + c] = v;
    return;
  }
  i -= S_B1;
  if (i < S_WTW) {
    int z = (int)(i / (128 * 256)); int rem = (int)(i % (128 * 256));
    int h = rem / 256, f = rem % 256;
    Wtw[i] = f2b(w_tw[((size_t)z * 256 + f) * 128 + h]);
    return;
  }
  i -= S_WTW;
  if (i < S_WG0) {
    int g = (int)(i / 512), f = (int)(i % 512);
    float v;
    if (g < 16) { int t = g >> 2, gg = g & 3; v = w_gate0[((size_t)t * 512 + f) * 4 + gg]; }
    else        { v = w_gsh0[(size_t)f * 10 + (g - 16)]; }
    WG0T[i] = f2b(v);
    return;
  }
  i -= S_WG0;
  if (i < S_WG1) {
    int t = (int)(i >> 10), gg = (int)((i >> 8) & 3), e = (int)(i & 255);
    WG1T[i] = w_gate1[((size_t)t * 256 + e) * 4 + gg];
    return;
  }
}

extern "C" void kernel_launch(void* const* d_in, const int* in_sizes, int n_in,
                              void* d_out, int out_size, void* d_ws, size_t ws_size,
                              hipStream_t stream)
{
  (void)in_sizes; (void)n_in; (void)out_size; (void)ws_size;
  const float* x       = (const float*)d_in[0];
  const float* w_task0 = (const float*)d_in[1];
  const float* b_task0 = (const float*)d_in[2];
  const float* w_sh0   = (const float*)d_in[3];
  const float* b_sh0   = (const float*)d_in[4];
  const float* w_gate0 = (const float*)d_in[5];
  const float* b_gate0 = (const float*)d_in[6];
  const float* w_gsh0  = (const float*)d_in[7];
  const float* b_gsh0  = (const float*)d_in[8];
  const float* w_task1 = (const float*)d_in[9];
  const float* b_task1 = (const float*)d_in[10];
  const float* w_sh1   = (const float*)d_in[11];
  const float* b_sh1   = (const float*)d_in[12];
  const float* w_gate1 = (const float*)d_in[13];
  const float* b_gate1 = (const float*)d_in[14];
  const float* w_tw    = (const float*)d_in[15];
  const float* b_tw    = (const float*)d_in[16];
  const float* w_out   = (const float*)d_in[17];
  const float* b_out   = (const float*)d_in[18];
  float* out = (float*)d_out;

  char* ws = (char*)d_ws;
  u16*   XB    = (u16*)  (ws + 0);            //  16,777,216  [16384][512] (read by gemm0+mix0)
  u16*   SH1E  = (u16*)  (ws + 0);            //  reuses XB (first write: gemm1, after mix0 done)
  u16*   WT0   = (u16*)  (ws + 16777216);     //   2,621,440  [2560][512]
  float* BIAS0 = (float*)(ws + 19398656);     //      10,240  [2560]
  u16*   WT1   = (u16*)  (ws + 19408896);     //   1,310,720  [5][512][256]
  float* BIAS1 = (float*)(ws + 20719616);     //      10,240  [5][512]
  u16*   WTW   = (u16*)  (ws + 20729856);     //     262,144  [4][128][256]
  u16*   WG0T  = (u16*)  (ws + 20992000);     //      26,624  [26][512] bf16
  float* WG1T  = (float*)(ws + 21018624);     //      16,384  [4][4][256] f32
  u16*   E0    = (u16*)  (ws + 21035008);     //  83,886,080  [16384][2560]
  u16*   T1SH  = (u16*)  (ws + 104921088);    //  41,943,040  [5][16384][256]
  u16*   E1    = (u16*)  (ws + 146864128);    //  67,108,864  [4][16384][512]
  float* G1S   = (float*)(ws + 213972992);    //   1,048,576  [16384][16]

  k_prep<<<12376, 256, 0, stream>>>(x, w_task0, b_task0, w_sh0, b_sh0,
      w_gate0, w_gsh0, w_task1, b_task1, w_sh1, b_sh1, w_gate1, w_tw,
      XB, WT0, BIAS0, WT1, BIAS1, WTW, WG0T, WG1T);
  k_gemm0<<<1280, 256, 0, stream>>>(XB, WT0, BIAS0, E0);
  k_mix0<<<2048, 256, 0, stream>>>(E0, XB, WG0T, b_gate0, b_gsh0, WG1T, b_gate1, T1SH, G1S);
  k_gemm1<<<1280, 256, 0, stream>>>(T1SH, WT1, BIAS1, E1, SH1E);
  k_tower2<<<dim3(128, 1, 4), 256, 0, stream>>>(E1, SH1E, G1S, WTW, b_tw, w_out, b_out, out);
}